// Round 18
// baseline (57.259 us; speedup 1.0000x reference)
//
#include <hip/hip_runtime.h>

#define T_ 4
#define C_ 3
#define H_ 128
#define W_ 128
#define PS_ 5
#define K_ 14
#define WS_ 15
#define SW_ 7
#define PW_ 2
#define RAD_ 9
#define HP_ 146          // H_ + 2*RAD_
#define NOFF 225
#define NPIX (T_*H_*W_)  // 65536
#define NQ 2

#define TILE 16
#define SPR 34           // sP rows/cols (pixels)
#define SPS 35           // sP row stride (float4s) - odd => bank rotation, minimal LDS
#define SSR 30           // sS rows/cols
#define SSS 33           // sS row stride
#define OB 12            // offsets per pipeline batch
#define NB 10            // batches per half (113 = 9*12+5; 112 = 9*12+4)
#define CSOG 324         // cs per-offset stride (16*20 + 4 pad)
#define CSBUF (OB*CSOG)  // 3888 floats per cs buffer
#define VOG 256          // vbuf per-offset stride (16 rows x 16)
#define VBUF (OB*VOG)    // 3072 floats per vbuf buffer

#define AT 8             // agg tile
#define APR 22           // staged P rows/cols (AT + 14)
#define APS 23           // staged P row stride (floats)
#define AWR 12           // staged wts rows (AT + 4)
#define AWS 20           // staged wts stride per pixel (floats)

typedef unsigned int u32;

// reflect-pad + normalize, fused (per-channel means cancel exactly; no subtraction)
__device__ __forceinline__ float4 load_refl(const float* __restrict__ noisy,
                                            int t, int py, int px) {
    int ry = py - RAD_; if (ry < 0) ry = -ry; if (ry > H_-1) ry = 2*(H_-1) - ry;
    int rx = px - RAD_; if (rx < 0) rx = -rx; if (rx > W_-1) rx = 2*(W_-1) - rx;
    const float* nt = noisy + (size_t)t*(C_*H_*W_) + ry*W_ + rx;
    float4 v;
    v.x = nt[0]          * (1.0f/127.5f) - 1.0f;
    v.y = nt[H_*W_]      * (1.0f/127.5f) - 1.0f;
    v.z = nt[2*(H_*W_)]  * (1.0f/127.5f) - 1.0f;
    v.w = 0.f;
    return v;
}

// batch (ob, len) for half q, visit index bi (center-out: q0 descending so self o=112 first)
__device__ __forceinline__ void batch_of(int q, int bi, int& ob, int& len) {
    if (q == 0) { int oi = NB-1 - bi; ob = oi*OB; len = (oi == NB-1) ? 5 : OB; }
    else        { ob = 113 + bi*OB;   len = (bi == NB-1) ? 4 : OB; }
}

// ---------------- Kernel 1: fused pad + S + distance + top-K over an offset half ----------------
// 512 threads, 3-stage software pipeline, ONE barrier per batch.
// Box sums computed as INDEPENDENT TREE SUMS (depth ~3), not sliding windows:
// the r17 sliding-window chains (~400 cyc/thread/batch in pass1) were the phase critical path.
// NOTE: __launch_bounds__ min-waves deliberately 4 — (512,6) capped VGPR at 40 and spilled (r13).
// d_true(pixel, o) = S_base + S_shift(o) - 2*box5(h_o)   (clamped >= 0)
// key = (bits(d) & 0xFFFFFF00) | o  -> uint order == (d, o) lexicographic
__global__ __launch_bounds__(512, 4) void fused_topk(const float* __restrict__ noisy,
                                                     uint4* __restrict__ pkey) {
    __shared__ __align__(16) float4 sP[SPR*SPS];     // 19040 B
    __shared__ __align__(16) float  sS[SSR*SSS];     //  3960 B
    __shared__ __align__(16) float  cs[2*CSBUF];     // 31104 B (also scratch: qsq/cq, exchange)
    __shared__ __align__(16) float  vb[2*VBUF];      // 24576 B

    const int tid = threadIdx.x;
    const int pix = tid & 255;
    const int part = tid >> 8;                // 0 or 1
    const int tx = pix & 15, ty = pix >> 4;
    const int z = blockIdx.z;                 // 0..7
    const int t = z >> 1, q = z & 1;
    const int i0 = blockIdx.y * TILE, j0 = blockIdx.x * TILE;

    // stage P tile directly from noisy (reflect + normalize fused); qsq computed inline
    {
        float* qsq = cs;               // [0, 1190)
        for (int e = tid; e < SPR*SPR; e += 512) {
            int r = e / SPR, c = e % SPR;
            float4 v = load_refl(noisy, t, i0 + r, j0 + c);
            sP[r*SPS + c] = v;
            qsq[r*35 + c] = v.x*v.x + v.y*v.y + v.z*v.z;
        }
    }
    __syncthreads();

    // in-block S: colq (30x34, stride 35) -> sS (30x30)
    {
        const float* qsq = cs;         // [0, 1190)
        float* cq  = cs + 1200;        // [1200, 2250)
        for (int e = tid; e < 30*34; e += 512) {
            int r = e / 34, c = e - r*34;
            const float* qp = &qsq[r*35 + c];
            cq[r*35 + c] = (qp[0] + qp[35]) + (qp[70] + qp[105]) + qp[140];
        }
        __syncthreads();
        for (int e = tid; e < 30*30; e += 512) {
            int r = e / 30, c = e - r*30;
            const float* cp = &cq[r*35 + c];
            sS[r*SSS + c] = (cp[0] + cp[1]) + (cp[2] + cp[3]) + cp[4];
        }
        __syncthreads();
    }

    const float Sbase = sS[(ty + SW_)*SSS + (tx + SW_)];

    // pass-1 role (tid < 240): thread = (offset og, column cc); base column in registers
    const int og = tid / 20;
    const int cc = tid - og*20;
    const bool p1thr = (tid < OB*20);          // 240
    float bx[20], by[20], bz[20];
    if (p1thr) {
        #pragma unroll
        for (int r = 0; r < 20; ++r) {
            float4 v = sP[(SW_ + r)*SPS + (cc + SW_)];
            bx[r] = v.x; by[r] = v.y; bz[r] = v.z;
        }
    }

    // pass-2 role (tid 256..447): thread = (offset slot p2g, row p2i)
    const int t2 = tid - 256;
    const bool p2thr = (t2 >= 0 && t2 < OB*16); // 192
    const int p2g = p2thr ? (t2 >> 4) : 0;
    const int p2i = t2 & 15;

    u32 kb[K_];
    #pragma unroll
    for (int k = 0; k < K_; ++k) kb[k] = 0xFFFFFFFFu;

    for (int i = 0; i <= NB + 1; ++i) {
        // ---- pass 1: batch i -> cs[i&1] (vertical box sums, independent tree sums)
        if (i < NB && p1thr) {
            int ob, len; batch_of(q, i, ob, len);
            if (og < len) {
                int o = ob + og;
                u32 oyu = (u32)o / 15u, oxu = (u32)o - oyu*15u;
                const float4* sp = &sP[(int)oyu*SPS + cc + (int)oxu];
                float* myv = &cs[(i & 1)*CSBUF + og*CSOG + cc];
                float h[20];
                #pragma unroll
                for (int r = 0; r < 20; ++r) {
                    float4 sv = sp[r*SPS];
                    h[r] = bx[r]*sv.x + by[r]*sv.y + bz[r]*sv.z;
                }
                float s2[19];
                #pragma unroll
                for (int r = 0; r < 19; ++r) s2[r] = h[r] + h[r+1];
                #pragma unroll
                for (int r = 0; r < 16; ++r) {
                    myv[r*20] = (s2[r] + s2[r+2]) + h[r+4];
                }
            }
        }
        // ---- pass 2: batch i-1: cs[(i-1)&1] -> vb[(i-1)&1] (horizontal box sums, tree)
        if (i >= 1 && i <= NB && p2thr) {
            int ob, len; batch_of(q, i - 1, ob, len);
            if (p2g < len) {
                const float* p2row = &cs[((i-1) & 1)*CSBUF + p2g*CSOG + p2i*20];
                float* vout = &vb[((i-1) & 1)*VBUF + p2g*VOG + p2i*16];
                float4 A = *(const float4*)(p2row);
                float4 B = *(const float4*)(p2row + 4);
                float4 Cv = *(const float4*)(p2row + 8);
                float4 Dv = *(const float4*)(p2row + 12);
                float4 Ev = *(const float4*)(p2row + 16);
                float v[20] = {A.x,A.y,A.z,A.w, B.x,B.y,B.z,B.w,
                               Cv.x,Cv.y,Cv.z,Cv.w, Dv.x,Dv.y,Dv.z,Dv.w,
                               Ev.x,Ev.y,Ev.z,Ev.w};
                float p2s[19];
                #pragma unroll
                for (int r = 0; r < 19; ++r) p2s[r] = v[r] + v[r+1];
                float rr[16];
                #pragma unroll
                for (int r = 0; r < 16; ++r) rr[r] = (p2s[r] + p2s[r+2]) + v[r+4];
                *(float4*)(vout)      = make_float4(rr[0],  rr[1],  rr[2],  rr[3]);
                *(float4*)(vout + 4)  = make_float4(rr[4],  rr[5],  rr[6],  rr[7]);
                *(float4*)(vout + 8)  = make_float4(rr[8],  rr[9],  rr[10], rr[11]);
                *(float4*)(vout + 12) = make_float4(rr[12], rr[13], rr[14], rr[15]);
            }
        }
        // ---- pass 3: batch i-2: distance + branchless med3 insert (all threads; depth-2)
        if (i >= 2) {
            int ob, len; batch_of(q, i - 2, ob, len);
            const float* vbase = &vb[((i-2) & 1)*VBUF + pix];
            for (int g = part; g < len; g += 2) {
                int o2 = ob + g;
                u32 oy2 = (u32)o2 / 15u, ox2 = (u32)o2 - oy2*15u;
                float V = vbase[g*VOG];
                float d = fmaxf(Sbase + sS[(ty + (int)oy2)*SSS + (tx + (int)ox2)] - 2.f*V, 0.f);
                u32 c = (__float_as_uint(d) & 0xFFFFFF00u) | (u32)o2;
                #pragma unroll
                for (int k = K_-1; k > 0; --k) kb[k] = min(kb[k], max(kb[k-1], c));
                kb[0] = min(kb[0], c);
            }
        }
        __syncthreads();
    }

    // cross-part merge: part1 publishes its sorted list; part0 merges and writes
    if (part == 1) {
        u32* ex = (u32*)cs + pix*20;   // stride 20 u32: 16B-aligned, spreads banks
        *(uint4*)(ex)      = make_uint4(kb[0],  kb[1],  kb[2],  kb[3]);
        *(uint4*)(ex + 4)  = make_uint4(kb[4],  kb[5],  kb[6],  kb[7]);
        *(uint4*)(ex + 8)  = make_uint4(kb[8],  kb[9],  kb[10], kb[11]);
        *(uint4*)(ex + 12) = make_uint4(kb[12], kb[13], 0xFFFFFFFFu, 0xFFFFFFFFu);
    }
    __syncthreads();
    if (part == 0) {
        const u32* ex = (const u32*)cs + pix*20;
        uint4 e0 = *(const uint4*)(ex);
        uint4 e1 = *(const uint4*)(ex + 4);
        uint4 e2 = *(const uint4*)(ex + 8);
        uint4 e3 = *(const uint4*)(ex + 12);
        u32 A[16] = {kb[0],kb[1],kb[2],kb[3],kb[4],kb[5],kb[6],kb[7],
                     kb[8],kb[9],kb[10],kb[11],kb[12],kb[13],0xFFFFFFFFu,0xFFFFFFFFu};
        u32 B[16] = {e0.x,e0.y,e0.z,e0.w, e1.x,e1.y,e1.z,e1.w,
                     e2.x,e2.y,e2.z,e2.w, e3.x,e3.y,e3.z,e3.w};
        #pragma unroll
        for (int i2 = 0; i2 < 16; ++i2) A[i2] = min(A[i2], B[15 - i2]);
        #define CEX(x,y) { u32 mn = min(A[x],A[y]); u32 mx = max(A[x],A[y]); A[x]=mn; A[y]=mx; }
        CEX(0,8) CEX(1,9) CEX(2,10) CEX(3,11) CEX(4,12) CEX(5,13) CEX(6,14) CEX(7,15)
        CEX(0,4) CEX(1,5) CEX(2,6) CEX(3,7) CEX(8,12) CEX(9,13) CEX(10,14) CEX(11,15)
        CEX(0,2) CEX(1,3) CEX(4,6) CEX(5,7) CEX(8,10) CEX(9,11) CEX(12,14) CEX(13,15)
        CEX(0,1) CEX(2,3) CEX(4,5) CEX(6,7) CEX(8,9) CEX(10,11) CEX(12,13) CEX(14,15)
        #undef CEX
        int px = ((t*H_ + i0 + ty)*W_ + j0 + tx);
        uint4* pk = pkey + ((size_t)q*NPIX + px)*4;
        pk[0] = make_uint4(A[0],  A[1],  A[2],  A[3]);
        pk[1] = make_uint4(A[4],  A[5],  A[6],  A[7]);
        pk[2] = make_uint4(A[8],  A[9],  A[10], A[11]);
        pk[3] = make_uint4(A[12], A[13], A[14], A[15]);
    }
}

// ---------------- Kernel 2: fused merge + softmax + gather-aggregate ----------------
// output padded coord y = i + PW_; contributing queries qi = y - a, a in [0,5)
__global__ __launch_bounds__(256, 4) void agg_kernel(const float* __restrict__ noisy,
                                                     const uint4* __restrict__ pkey,
                                                     const float* __restrict__ sigma,
                                                     float* __restrict__ out) {
    __shared__ float sPx[APR*APS];
    __shared__ float sPy[APR*APS];
    __shared__ float sPz[APR*APS];
    __shared__ float sWt[AWR*AWR*AWS];
    __shared__ uint4 sIx[AWR*AWR];     // pre-decoded (dy<<4|dx) bytes

    const int tid = threadIdx.x;
    const int part = tid & 3;
    const int lp = tid >> 2;                  // 0..63 local pixel
    const int tx = lp & 7, ty = lp >> 3;
    const int i0 = blockIdx.y * AT, j0 = blockIdx.x * AT;
    const int t = blockIdx.z;

    // stage P planes directly from noisy (reflect + normalize fused)
    for (int e = tid; e < APR*APR; e += 256) {
        int r = e / APR, c = e - r*APR;
        float4 v = load_refl(noisy, t, i0 + 2 + r, j0 + 2 + c);
        sPx[r*APS + c] = v.x;
        sPy[r*APS + c] = v.y;
        sPz[r*APS + c] = v.z;
    }

    // merge phase: one thread per staged neighbor (qi = i0 - 2 + r)
    if (tid < AWR*AWR) {
        int r = tid / AWR, c = tid - r*AWR;
        int qi = i0 - 2 + r, qj = j0 - 2 + c;
        if (qi >= 0 && qi < H_ && qj >= 0 && qj < W_) {
            size_t px = ((size_t)t*H_ + qi)*W_ + qj;
            // Batcher bitonic set-merge of the 2 sorted ascending 16-lists
            u32 A[16];
            {
                const uint4* pk = pkey + px*4;
                uint4 a0=pk[0], a1=pk[1], a2=pk[2], a3=pk[3];
                A[0]=a0.x; A[1]=a0.y; A[2]=a0.z; A[3]=a0.w;
                A[4]=a1.x; A[5]=a1.y; A[6]=a1.z; A[7]=a1.w;
                A[8]=a2.x; A[9]=a2.y; A[10]=a2.z; A[11]=a2.w;
                A[12]=a3.x; A[13]=a3.y; A[14]=a3.z; A[15]=a3.w;
            }
            {
                const uint4* pk = pkey + ((size_t)NPIX + px)*4;
                uint4 b0=pk[0], b1=pk[1], b2=pk[2], b3=pk[3];
                u32 B[16] = {b0.x,b0.y,b0.z,b0.w, b1.x,b1.y,b1.z,b1.w,
                             b2.x,b2.y,b2.z,b2.w, b3.x,b3.y,b3.z,b3.w};
                #pragma unroll
                for (int i2 = 0; i2 < 16; ++i2) A[i2] = min(A[i2], B[15 - i2]);
                #define CEX(x,y) { u32 mn = min(A[x],A[y]); u32 mx = max(A[x],A[y]); A[x]=mn; A[y]=mx; }
                CEX(0,8) CEX(1,9) CEX(2,10) CEX(3,11) CEX(4,12) CEX(5,13) CEX(6,14) CEX(7,15)
                CEX(0,4) CEX(1,5) CEX(2,6) CEX(3,7) CEX(8,12) CEX(9,13) CEX(10,14) CEX(11,15)
                CEX(0,2) CEX(1,3) CEX(4,6) CEX(5,7) CEX(8,10) CEX(9,11) CEX(12,14) CEX(13,15)
                CEX(0,1) CEX(2,3) CEX(4,5) CEX(6,7) CEX(8,9) CEX(10,11) CEX(12,13) CEX(14,15)
                #undef CEX
            }
            float sig = sigma[0] * (1.0f/255.0f) * 2.0f;
            float denom = 2.0f * (float)(C_*PS_*PS_) * (sig*sig) + 1e-8f;
            float d0 = __uint_as_float(A[0] & 0xFFFFFF00u);
            float w[K_]; float sum = 0.f;
            #pragma unroll
            for (int k = 0; k < K_; ++k) {
                float d = __uint_as_float(A[k] & 0xFFFFFF00u);
                w[k] = expf(-(d - d0) / denom); sum += w[k];
            }
            float inv = 1.0f / sum;
            float4* dst = (float4*)&sWt[tid*AWS];
            dst[0] = make_float4(w[0]*inv,  w[1]*inv,  w[2]*inv,  w[3]*inv);
            dst[1] = make_float4(w[4]*inv,  w[5]*inv,  w[6]*inv,  w[7]*inv);
            dst[2] = make_float4(w[8]*inv,  w[9]*inv,  w[10]*inv, w[11]*inv);
            dst[3] = make_float4(w[12]*inv, w[13]*inv, 0.f, 0.f);
            // pre-decode offsets: byte = (dy<<4)|dx
            u32 db[K_];
            #pragma unroll
            for (int k = 0; k < K_; ++k) {
                u32 o_ = A[k] & 255u;
                u32 dy = o_ / 15u, dx = o_ - dy*15u;
                db[k] = (dy << 4) | dx;
            }
            uint4 iv;
            iv.x = db[0]  | (db[1]<<8)  | (db[2]<<16)  | (db[3]<<24);
            iv.y = db[4]  | (db[5]<<8)  | (db[6]<<16)  | (db[7]<<24);
            iv.z = db[8]  | (db[9]<<8)  | (db[10]<<16) | (db[11]<<24);
            iv.w = db[12] | (db[13]<<8);
            sIx[tid] = iv;
        }
    }
    __syncthreads();

    const int i = i0 + ty, j = j0 + tx;
    float s0 = 0.f, s1 = 0.f, s2 = 0.f;
    for (int ab = part; ab < 25; ab += 4) {
        int a = ab / 5, b = ab % 5;
        int qi = i + PW_ - a, qj = j + PW_ - b;
        if (qi < 0 || qi >= H_ || qj < 0 || qj >= W_) continue;
        int le = (ty + 4 - a)*AWR + (tx + 4 - b);   // (qi - (i0-2)) = ty + 4 - a
        const float4* wv = (const float4*)&sWt[le*AWS];
        float4 wa = wv[0], wb = wv[1], wc = wv[2], wd = wv[3];
        uint4 ip = sIx[le];
        #define ACC(wval, bbits) { \
            u32 b_ = (bbits); \
            int li = (ty + (int)(b_ >> 4))*APS + tx + (int)(b_ & 15u); \
            float w_ = (wval); \
            s0 += w_ * sPx[li]; s1 += w_ * sPy[li]; s2 += w_ * sPz[li]; }
        ACC(wa.x, ip.x & 255u);       ACC(wa.y, (ip.x>>8) & 255u);
        ACC(wa.z, (ip.x>>16) & 255u); ACC(wa.w, ip.x>>24);
        ACC(wb.x, ip.y & 255u);       ACC(wb.y, (ip.y>>8) & 255u);
        ACC(wb.z, (ip.y>>16) & 255u); ACC(wb.w, ip.y>>24);
        ACC(wc.x, ip.z & 255u);       ACC(wc.y, (ip.z>>8) & 255u);
        ACC(wc.z, (ip.z>>16) & 255u); ACC(wc.w, ip.z>>24);
        ACC(wd.x, ip.w & 255u);       ACC(wd.y, (ip.w>>8) & 255u);
        #undef ACC
    }

    s0 += __shfl_xor(s0, 1, 64); s0 += __shfl_xor(s0, 2, 64);
    s1 += __shfl_xor(s1, 1, 64); s1 += __shfl_xor(s1, 2, 64);
    s2 += __shfl_xor(s2, 1, 64); s2 += __shfl_xor(s2, 2, 64);

    if (part == 0) {
        // analytic count: a valid iff 0 <= i+2-a <= 127, a in [0,5)
        int na = min(4, i + 2) - max(0, i - 125) + 1;
        int nb = min(4, j + 2) - max(0, j - 125) + 1;
        float invc = 1.0f / ((float)(na * nb) + 1e-10f);
        size_t obase = (size_t)t*(C_*H_*W_) + (size_t)i*W_ + j;
        out[obase]             = 127.5f * (s0*invc + 1.0f);
        out[obase +   H_*W_]   = 127.5f * (s1*invc + 1.0f);
        out[obase + 2*(H_*W_)] = 127.5f * (s2*invc + 1.0f);
    }
}

extern "C" void kernel_launch(void* const* d_in, const int* in_sizes, int n_in,
                              void* d_out, int out_size, void* d_ws, size_t ws_size,
                              hipStream_t stream) {
    const float* noisy = (const float*)d_in[0];
    const float* sigma = (const float*)d_in[1];
    float* out = (float*)d_out;
    float* ws  = (float*)d_ws;

    // ws layout: pkey only = 2*NPIX*16 u32 = 8 MB
    uint4* pkey = (uint4*)ws;

    hipLaunchKernelGGL(fused_topk, dim3(W_/TILE, H_/TILE, T_*NQ), dim3(512), 0, stream,
                       noisy, pkey);

    hipLaunchKernelGGL(agg_kernel, dim3(W_/AT, H_/AT, T_), dim3(256), 0, stream,
                       noisy, pkey, sigma, out);
}

// Round 19
// 54.207 us; speedup vs baseline: 1.0563x; 1.0563x over previous
//
#include <hip/hip_runtime.h>

#define T_ 4
#define C_ 3
#define H_ 128
#define W_ 128
#define PS_ 5
#define K_ 14
#define WS_ 15
#define SW_ 7
#define PW_ 2
#define RAD_ 9
#define HP_ 146          // H_ + 2*RAD_
#define NOFF 225
#define NPIX (T_*H_*W_)  // 65536
#define NQ 2

#define TILE 16
#define SPR 34           // sP rows/cols (pixels)
#define SPS 35           // sP row stride (float4s) - odd => bank rotation, minimal LDS
#define SSR 30           // sS rows/cols
#define SSS 33           // sS row stride
#define OB 12            // offsets per pipeline batch
#define NB 10            // batches per half (113 = 9*12+5; 112 = 9*12+4)
#define CSOG 324         // cs per-offset stride (16*20 + 4 pad)
#define CSBUF (OB*CSOG)  // 3888 floats per cs buffer
#define VOG 256          // vbuf per-offset stride (16 rows x 16)
#define VBUF (OB*VOG)    // 3072 floats per vbuf buffer

#define AT 8             // agg tile
#define APR 22           // staged P rows/cols (AT + 14)
#define APS 23           // staged P row stride (floats)
#define AWR 12           // staged wts rows (AT + 4)
#define AWS 20           // staged wts stride per pixel (floats)

typedef unsigned int u32;

// reflect-pad + normalize, fused (per-channel means cancel exactly; no subtraction)
__device__ __forceinline__ float4 load_refl(const float* __restrict__ noisy,
                                            int t, int py, int px) {
    int ry = py - RAD_; if (ry < 0) ry = -ry; if (ry > H_-1) ry = 2*(H_-1) - ry;
    int rx = px - RAD_; if (rx < 0) rx = -rx; if (rx > W_-1) rx = 2*(W_-1) - rx;
    const float* nt = noisy + (size_t)t*(C_*H_*W_) + ry*W_ + rx;
    float4 v;
    v.x = nt[0]          * (1.0f/127.5f) - 1.0f;
    v.y = nt[H_*W_]      * (1.0f/127.5f) - 1.0f;
    v.z = nt[2*(H_*W_)]  * (1.0f/127.5f) - 1.0f;
    v.w = 0.f;
    return v;
}

// batch (ob, len) for half q, visit index bi (center-out: q0 descending so self o=112 first)
__device__ __forceinline__ void batch_of(int q, int bi, int& ob, int& len) {
    if (q == 0) { int oi = NB-1 - bi; ob = oi*OB; len = (oi == NB-1) ? 5 : OB; }
    else        { ob = 113 + bi*OB;   len = (bi == NB-1) ? 4 : OB; }
}

// ---------------- Kernel 1: fused pad + S + distance + top-K over an offset half ----------------
// 512 threads, 3-stage software pipeline, ONE barrier per batch, WAVE-SPECIALIZED:
//   waves 0-3 (tid<240): pass1 only (LDS-heavy)      -> cs[i&1]
//   waves 4-6 (tid 256..447): pass2 (cs -> vb)
//   waves 4-7 (tid 256..511): pass3 — ONE thread per pixel, ALL offsets (VALU-heavy)
// Heterogeneous waves co-schedule on a SIMD (LDS + VALU pipes overlap); no cross-part
// merge epilogue needed (kb complete per pixel on threads 256+).
// NOTE: __launch_bounds__ min-waves deliberately 4 — (512,6) capped VGPR at 40 and spilled (r13).
// d_true(pixel, o) = S_base + S_shift(o) - 2*box5(h_o)   (clamped >= 0)
// key = (bits(d) & 0xFFFFFF00) | o  -> uint order == (d, o) lexicographic
__global__ __launch_bounds__(512, 4) void fused_topk(const float* __restrict__ noisy,
                                                     uint4* __restrict__ pkey) {
    __shared__ __align__(16) float4 sP[SPR*SPS];     // 19040 B
    __shared__ __align__(16) float  sS[SSR*SSS];     //  3960 B
    __shared__ __align__(16) float  cs[2*CSBUF];     // 31104 B (also scratch: qsq/cq)
    __shared__ __align__(16) float  vb[2*VBUF];      // 24576 B

    const int tid = threadIdx.x;
    const int z = blockIdx.z;                 // 0..7
    const int t = z >> 1, q = z & 1;
    const int i0 = blockIdx.y * TILE, j0 = blockIdx.x * TILE;

    // stage P tile directly from noisy (reflect + normalize fused); qsq computed inline
    {
        float* qsq = cs;               // [0, 1190)
        for (int e = tid; e < SPR*SPR; e += 512) {
            int r = e / SPR, c = e % SPR;
            float4 v = load_refl(noisy, t, i0 + r, j0 + c);
            sP[r*SPS + c] = v;
            qsq[r*35 + c] = v.x*v.x + v.y*v.y + v.z*v.z;
        }
    }
    __syncthreads();

    // in-block S: colq (30x34, stride 35) -> sS (30x30)
    {
        const float* qsq = cs;         // [0, 1190)
        float* cq  = cs + 1200;        // [1200, 2250)
        for (int e = tid; e < 30*34; e += 512) {
            int r = e / 34, c = e - r*34;
            const float* qp = &qsq[r*35 + c];
            cq[r*35 + c] = qp[0] + qp[35] + qp[70] + qp[105] + qp[140];
        }
        __syncthreads();
        for (int e = tid; e < 30*30; e += 512) {
            int r = e / 30, c = e - r*30;
            const float* cp = &cq[r*35 + c];
            sS[r*SSS + c] = cp[0] + cp[1] + cp[2] + cp[3] + cp[4];
        }
        __syncthreads();
    }

    // pass-1 role (tid < 240): thread = (offset og, column cc); base column in registers
    const int og = tid / 20;
    const int cc = tid - og*20;
    const bool p1thr = (tid < OB*20);          // 240
    float bx[20], by[20], bz[20];
    if (p1thr) {
        #pragma unroll
        for (int r = 0; r < 20; ++r) {
            float4 v = sP[(SW_ + r)*SPS + (cc + SW_)];
            bx[r] = v.x; by[r] = v.y; bz[r] = v.z;
        }
    }

    // pass-2 role (tid 256..447): thread = (offset slot p2g, row p2i)
    const int t2 = tid - 256;
    const bool p2thr = (t2 >= 0 && t2 < OB*16); // 192
    const int p2g = p2thr ? (t2 >> 4) : 0;
    const int p2i = t2 & 15;

    // pass-3 role (tid >= 256): one thread per pixel, all offsets
    const bool p3thr = (tid >= 256);
    const int pix3 = tid & 255;
    const int tx3 = pix3 & 15, ty3 = pix3 >> 4;
    const float Sbase = sS[(ty3 + SW_)*SSS + (tx3 + SW_)];

    u32 kb[K_];
    #pragma unroll
    for (int k = 0; k < K_; ++k) kb[k] = 0xFFFFFFFFu;

    for (int i = 0; i <= NB + 1; ++i) {
        // ---- pass 1: batch i -> cs[i&1] (vertical box sums, register sliding window)
        if (i < NB && p1thr) {
            int ob, len; batch_of(q, i, ob, len);
            if (og < len) {
                int o = ob + og;
                u32 oyu = (u32)o / 15u, oxu = (u32)o - oyu*15u;
                const float4* sp = &sP[(int)oyu*SPS + cc + (int)oxu];
                float* myv = &cs[(i & 1)*CSBUF + og*CSOG + cc];
                float ring[5]; float run = 0.f;
                #pragma unroll
                for (int r = 0; r < 20; ++r) {
                    float4 sv = sp[r*SPS];
                    float hr = bx[r]*sv.x + by[r]*sv.y + bz[r]*sv.z;
                    if (r < 5) run += hr;
                    else       run += hr - ring[r % 5];
                    ring[r % 5] = hr;
                    if (r >= 4) myv[(r-4)*20] = run;
                }
            }
        }
        // ---- pass 2: batch i-1: cs[(i-1)&1] -> vb[(i-1)&1] (horizontal box sums)
        if (i >= 1 && i <= NB && p2thr) {
            int ob, len; batch_of(q, i - 1, ob, len);
            if (p2g < len) {
                const float* p2row = &cs[((i-1) & 1)*CSBUF + p2g*CSOG + p2i*20];
                float* vout = &vb[((i-1) & 1)*VBUF + p2g*VOG + p2i*16];
                float4 A = *(const float4*)(p2row);
                float4 B = *(const float4*)(p2row + 4);
                float4 Cv = *(const float4*)(p2row + 8);
                float4 Dv = *(const float4*)(p2row + 12);
                float4 Ev = *(const float4*)(p2row + 16);
                float v0=A.x,v1=A.y,v2=A.z,v3=A.w,v4=B.x,v5=B.y,v6=B.z,v7=B.w;
                float v8=Cv.x,v9=Cv.y,v10=Cv.z,v11=Cv.w,v12=Dv.x,v13=Dv.y,v14=Dv.z,v15=Dv.w;
                float v16=Ev.x,v17=Ev.y,v18=Ev.z,v19=Ev.w;
                float r0 = v0+v1+v2+v3+v4;
                float r1 = r0 + v5 - v0;
                float r2 = r1 + v6 - v1;
                float r3 = r2 + v7 - v2;
                float r4 = r3 + v8 - v3;
                float r5 = r4 + v9 - v4;
                float r6 = r5 + v10 - v5;
                float r7 = r6 + v11 - v6;
                float r8 = r7 + v12 - v7;
                float r9 = r8 + v13 - v8;
                float r10 = r9 + v14 - v9;
                float r11 = r10 + v15 - v10;
                float r12 = r11 + v16 - v11;
                float r13 = r12 + v17 - v12;
                float r14 = r13 + v18 - v13;
                float r15 = r14 + v19 - v14;
                *(float4*)(vout)      = make_float4(r0, r1, r2, r3);
                *(float4*)(vout + 4)  = make_float4(r4, r5, r6, r7);
                *(float4*)(vout + 8)  = make_float4(r8, r9, r10, r11);
                *(float4*)(vout + 12) = make_float4(r12, r13, r14, r15);
            }
        }
        // ---- pass 3: batch i-2: distance + branchless med3 insert (waves 4-7, all offsets)
        if (i >= 2 && p3thr) {
            int ob, len; batch_of(q, i - 2, ob, len);
            const float* vbase = &vb[((i-2) & 1)*VBUF + pix3];
            for (int g = 0; g < len; ++g) {
                int o2 = ob + g;
                u32 oy2 = (u32)o2 / 15u, ox2 = (u32)o2 - oy2*15u;
                float V = vbase[g*VOG];
                float d = fmaxf(Sbase + sS[(ty3 + (int)oy2)*SSS + (tx3 + (int)ox2)] - 2.f*V, 0.f);
                u32 c = (__float_as_uint(d) & 0xFFFFFF00u) | (u32)o2;
                #pragma unroll
                for (int k = K_-1; k > 0; --k) kb[k] = min(kb[k], max(kb[k-1], c));
                kb[0] = min(kb[0], c);
            }
        }
        __syncthreads();
    }

    // final write: threads 256+ hold the complete sorted list for their pixel
    if (p3thr) {
        int px = ((t*H_ + i0 + ty3)*W_ + j0 + tx3);
        uint4* pk = pkey + ((size_t)q*NPIX + px)*4;
        pk[0] = make_uint4(kb[0],  kb[1],  kb[2],  kb[3]);
        pk[1] = make_uint4(kb[4],  kb[5],  kb[6],  kb[7]);
        pk[2] = make_uint4(kb[8],  kb[9],  kb[10], kb[11]);
        pk[3] = make_uint4(kb[12], kb[13], 0xFFFFFFFFu, 0xFFFFFFFFu);
    }
}

// ---------------- Kernel 2: fused merge + softmax + gather-aggregate ----------------
// output padded coord y = i + PW_; contributing queries qi = y - a, a in [0,5)
__global__ __launch_bounds__(256, 4) void agg_kernel(const float* __restrict__ noisy,
                                                     const uint4* __restrict__ pkey,
                                                     const float* __restrict__ sigma,
                                                     float* __restrict__ out) {
    __shared__ float sPx[APR*APS];
    __shared__ float sPy[APR*APS];
    __shared__ float sPz[APR*APS];
    __shared__ float sWt[AWR*AWR*AWS];
    __shared__ uint4 sIx[AWR*AWR];     // pre-decoded (dy<<4|dx) bytes

    const int tid = threadIdx.x;
    const int part = tid & 3;
    const int lp = tid >> 2;                  // 0..63 local pixel
    const int tx = lp & 7, ty = lp >> 3;
    const int i0 = blockIdx.y * AT, j0 = blockIdx.x * AT;
    const int t = blockIdx.z;

    // stage P planes directly from noisy (reflect + normalize fused)
    for (int e = tid; e < APR*APR; e += 256) {
        int r = e / APR, c = e - r*APR;
        float4 v = load_refl(noisy, t, i0 + 2 + r, j0 + 2 + c);
        sPx[r*APS + c] = v.x;
        sPy[r*APS + c] = v.y;
        sPz[r*APS + c] = v.z;
    }

    // merge phase: one thread per staged neighbor (qi = i0 - 2 + r)
    if (tid < AWR*AWR) {
        int r = tid / AWR, c = tid - r*AWR;
        int qi = i0 - 2 + r, qj = j0 - 2 + c;
        if (qi >= 0 && qi < H_ && qj >= 0 && qj < W_) {
            size_t px = ((size_t)t*H_ + qi)*W_ + qj;
            // Batcher bitonic set-merge of the 2 sorted ascending 16-lists
            u32 A[16];
            {
                const uint4* pk = pkey + px*4;
                uint4 a0=pk[0], a1=pk[1], a2=pk[2], a3=pk[3];
                A[0]=a0.x; A[1]=a0.y; A[2]=a0.z; A[3]=a0.w;
                A[4]=a1.x; A[5]=a1.y; A[6]=a1.z; A[7]=a1.w;
                A[8]=a2.x; A[9]=a2.y; A[10]=a2.z; A[11]=a2.w;
                A[12]=a3.x; A[13]=a3.y; A[14]=a3.z; A[15]=a3.w;
            }
            {
                const uint4* pk = pkey + ((size_t)NPIX + px)*4;
                uint4 b0=pk[0], b1=pk[1], b2=pk[2], b3=pk[3];
                u32 B[16] = {b0.x,b0.y,b0.z,b0.w, b1.x,b1.y,b1.z,b1.w,
                             b2.x,b2.y,b2.z,b2.w, b3.x,b3.y,b3.z,b3.w};
                #pragma unroll
                for (int i2 = 0; i2 < 16; ++i2) A[i2] = min(A[i2], B[15 - i2]);
                #define CEX(x,y) { u32 mn = min(A[x],A[y]); u32 mx = max(A[x],A[y]); A[x]=mn; A[y]=mx; }
                CEX(0,8) CEX(1,9) CEX(2,10) CEX(3,11) CEX(4,12) CEX(5,13) CEX(6,14) CEX(7,15)
                CEX(0,4) CEX(1,5) CEX(2,6) CEX(3,7) CEX(8,12) CEX(9,13) CEX(10,14) CEX(11,15)
                CEX(0,2) CEX(1,3) CEX(4,6) CEX(5,7) CEX(8,10) CEX(9,11) CEX(12,14) CEX(13,15)
                CEX(0,1) CEX(2,3) CEX(4,5) CEX(6,7) CEX(8,9) CEX(10,11) CEX(12,13) CEX(14,15)
                #undef CEX
            }
            float sig = sigma[0] * (1.0f/255.0f) * 2.0f;
            float denom = 2.0f * (float)(C_*PS_*PS_) * (sig*sig) + 1e-8f;
            float d0 = __uint_as_float(A[0] & 0xFFFFFF00u);
            float w[K_]; float sum = 0.f;
            #pragma unroll
            for (int k = 0; k < K_; ++k) {
                float d = __uint_as_float(A[k] & 0xFFFFFF00u);
                w[k] = expf(-(d - d0) / denom); sum += w[k];
            }
            float inv = 1.0f / sum;
            float4* dst = (float4*)&sWt[tid*AWS];
            dst[0] = make_float4(w[0]*inv,  w[1]*inv,  w[2]*inv,  w[3]*inv);
            dst[1] = make_float4(w[4]*inv,  w[5]*inv,  w[6]*inv,  w[7]*inv);
            dst[2] = make_float4(w[8]*inv,  w[9]*inv,  w[10]*inv, w[11]*inv);
            dst[3] = make_float4(w[12]*inv, w[13]*inv, 0.f, 0.f);
            // pre-decode offsets: byte = (dy<<4)|dx
            u32 db[K_];
            #pragma unroll
            for (int k = 0; k < K_; ++k) {
                u32 o_ = A[k] & 255u;
                u32 dy = o_ / 15u, dx = o_ - dy*15u;
                db[k] = (dy << 4) | dx;
            }
            uint4 iv;
            iv.x = db[0]  | (db[1]<<8)  | (db[2]<<16)  | (db[3]<<24);
            iv.y = db[4]  | (db[5]<<8)  | (db[6]<<16)  | (db[7]<<24);
            iv.z = db[8]  | (db[9]<<8)  | (db[10]<<16) | (db[11]<<24);
            iv.w = db[12] | (db[13]<<8);
            sIx[tid] = iv;
        }
    }
    __syncthreads();

    const int i = i0 + ty, j = j0 + tx;
    float s0 = 0.f, s1 = 0.f, s2 = 0.f;
    for (int ab = part; ab < 25; ab += 4) {
        int a = ab / 5, b = ab % 5;
        int qi = i + PW_ - a, qj = j + PW_ - b;
        if (qi < 0 || qi >= H_ || qj < 0 || qj >= W_) continue;
        int le = (ty + 4 - a)*AWR + (tx + 4 - b);   // (qi - (i0-2)) = ty + 4 - a
        const float4* wv = (const float4*)&sWt[le*AWS];
        float4 wa = wv[0], wb = wv[1], wc = wv[2], wd = wv[3];
        uint4 ip = sIx[le];
        #define ACC(wval, bbits) { \
            u32 b_ = (bbits); \
            int li = (ty + (int)(b_ >> 4))*APS + tx + (int)(b_ & 15u); \
            float w_ = (wval); \
            s0 += w_ * sPx[li]; s1 += w_ * sPy[li]; s2 += w_ * sPz[li]; }
        ACC(wa.x, ip.x & 255u);       ACC(wa.y, (ip.x>>8) & 255u);
        ACC(wa.z, (ip.x>>16) & 255u); ACC(wa.w, ip.x>>24);
        ACC(wb.x, ip.y & 255u);       ACC(wb.y, (ip.y>>8) & 255u);
        ACC(wb.z, (ip.y>>16) & 255u); ACC(wb.w, ip.y>>24);
        ACC(wc.x, ip.z & 255u);       ACC(wc.y, (ip.z>>8) & 255u);
        ACC(wc.z, (ip.z>>16) & 255u); ACC(wc.w, ip.z>>24);
        ACC(wd.x, ip.w & 255u);       ACC(wd.y, (ip.w>>8) & 255u);
        #undef ACC
    }

    s0 += __shfl_xor(s0, 1, 64); s0 += __shfl_xor(s0, 2, 64);
    s1 += __shfl_xor(s1, 1, 64); s1 += __shfl_xor(s1, 2, 64);
    s2 += __shfl_xor(s2, 1, 64); s2 += __shfl_xor(s2, 2, 64);

    if (part == 0) {
        // analytic count: a valid iff 0 <= i+2-a <= 127, a in [0,5)
        int na = min(4, i + 2) - max(0, i - 125) + 1;
        int nb = min(4, j + 2) - max(0, j - 125) + 1;
        float invc = 1.0f / ((float)(na * nb) + 1e-10f);
        size_t obase = (size_t)t*(C_*H_*W_) + (size_t)i*W_ + j;
        out[obase]             = 127.5f * (s0*invc + 1.0f);
        out[obase +   H_*W_]   = 127.5f * (s1*invc + 1.0f);
        out[obase + 2*(H_*W_)] = 127.5f * (s2*invc + 1.0f);
    }
}

extern "C" void kernel_launch(void* const* d_in, const int* in_sizes, int n_in,
                              void* d_out, int out_size, void* d_ws, size_t ws_size,
                              hipStream_t stream) {
    const float* noisy = (const float*)d_in[0];
    const float* sigma = (const float*)d_in[1];
    float* out = (float*)d_out;
    float* ws  = (float*)d_ws;

    // ws layout: pkey only = 2*NPIX*16 u32 = 8 MB
    uint4* pkey = (uint4*)ws;

    hipLaunchKernelGGL(fused_topk, dim3(W_/TILE, H_/TILE, T_*NQ), dim3(512), 0, stream,
                       noisy, pkey);

    hipLaunchKernelGGL(agg_kernel, dim3(W_/AT, H_/AT, T_), dim3(256), 0, stream,
                       noisy, pkey, sigma, out);
}

// Round 20
// 50.985 us; speedup vs baseline: 1.1231x; 1.0632x over previous
//
#include <hip/hip_runtime.h>

#define T_ 4
#define C_ 3
#define H_ 128
#define W_ 128
#define PS_ 5
#define K_ 14
#define WS_ 15
#define SW_ 7
#define PW_ 2
#define RAD_ 9
#define HP_ 146          // H_ + 2*RAD_
#define NOFF 225
#define NPIX (T_*H_*W_)  // 65536
#define NQ 2

#define TILE 16
#define SPR 34           // sP rows/cols (pixels)
#define SPS 35           // sP row stride (float4s) - odd => bank rotation, minimal LDS
#define SSR 30           // sS rows/cols
#define SSS 33           // sS row stride
#define OB 12            // offsets per pipeline batch
#define NB 10            // batches per half (113 = 9*12+5; 112 = 9*12+4)
#define CSOG 324         // cs per-offset stride (16*20 + 4 pad)
#define CSBUF (OB*CSOG)  // 3888 floats per cs buffer
#define VOG 256          // vbuf per-offset stride (16 rows x 16)
#define VBUF (OB*VOG)    // 3072 floats per vbuf buffer

#define AT 8             // agg tile
#define APR 22           // staged P rows/cols (AT + 14)
#define APS 23           // staged P row stride (elements)
#define AWR 12           // staged wts rows (AT + 4)
#define AWS 20           // staged wts stride per pixel (floats)

typedef unsigned int u32;

// reflect-pad + normalize, fused (per-channel means cancel exactly; no subtraction)
__device__ __forceinline__ float4 load_refl(const float* __restrict__ noisy,
                                            int t, int py, int px) {
    int ry = py - RAD_; if (ry < 0) ry = -ry; if (ry > H_-1) ry = 2*(H_-1) - ry;
    int rx = px - RAD_; if (rx < 0) rx = -rx; if (rx > W_-1) rx = 2*(W_-1) - rx;
    const float* nt = noisy + (size_t)t*(C_*H_*W_) + ry*W_ + rx;
    float4 v;
    v.x = nt[0]          * (1.0f/127.5f) - 1.0f;
    v.y = nt[H_*W_]      * (1.0f/127.5f) - 1.0f;
    v.z = nt[2*(H_*W_)]  * (1.0f/127.5f) - 1.0f;
    v.w = 0.f;
    return v;
}

// batch (ob, len) for half q, visit index bi (center-out: q0 descending so self o=112 first)
__device__ __forceinline__ void batch_of(int q, int bi, int& ob, int& len) {
    if (q == 0) { int oi = NB-1 - bi; ob = oi*OB; len = (oi == NB-1) ? 5 : OB; }
    else        { ob = 113 + bi*OB;   len = (bi == NB-1) ? 4 : OB; }
}

// ---------------- Kernel 1: fused pad + S + distance + top-K over an offset half ----------------
// 512 threads, 3-stage software pipeline, ONE barrier per batch, WAVE-SPECIALIZED:
//   waves 0-3 (tid<240): pass1 only (LDS-heavy)      -> cs[i&1]
//   waves 4-6 (tid 256..447): pass2 (cs -> vb)
//   waves 4-7 (tid 256..511): pass3 — ONE thread per pixel, ALL offsets (VALU-heavy)
// NOTE: __launch_bounds__ min-waves deliberately 4 — (512,6) capped VGPR at 40 and spilled (r13).
// d_true(pixel, o) = S_base + S_shift(o) - 2*box5(h_o)   (clamped >= 0)
// key = (bits(d) & 0xFFFFFF00) | o  -> uint order == (d, o) lexicographic
__global__ __launch_bounds__(512, 4) void fused_topk(const float* __restrict__ noisy,
                                                     uint4* __restrict__ pkey) {
    __shared__ __align__(16) float4 sP[SPR*SPS];     // 19040 B
    __shared__ __align__(16) float  sS[SSR*SSS];     //  3960 B
    __shared__ __align__(16) float  cs[2*CSBUF];     // 31104 B (also scratch: qsq/cq)
    __shared__ __align__(16) float  vb[2*VBUF];      // 24576 B

    const int tid = threadIdx.x;
    const int z = blockIdx.z;                 // 0..7
    const int t = z >> 1, q = z & 1;
    const int i0 = blockIdx.y * TILE, j0 = blockIdx.x * TILE;

    // stage P tile directly from noisy (reflect + normalize fused); qsq computed inline
    {
        float* qsq = cs;               // [0, 1190)
        for (int e = tid; e < SPR*SPR; e += 512) {
            int r = e / SPR, c = e % SPR;
            float4 v = load_refl(noisy, t, i0 + r, j0 + c);
            sP[r*SPS + c] = v;
            qsq[r*35 + c] = v.x*v.x + v.y*v.y + v.z*v.z;
        }
    }
    __syncthreads();

    // in-block S: colq (30x34, stride 35) -> sS (30x30)
    {
        const float* qsq = cs;         // [0, 1190)
        float* cq  = cs + 1200;        // [1200, 2250)
        for (int e = tid; e < 30*34; e += 512) {
            int r = e / 34, c = e - r*34;
            const float* qp = &qsq[r*35 + c];
            cq[r*35 + c] = qp[0] + qp[35] + qp[70] + qp[105] + qp[140];
        }
        __syncthreads();
        for (int e = tid; e < 30*30; e += 512) {
            int r = e / 30, c = e - r*30;
            const float* cp = &cq[r*35 + c];
            sS[r*SSS + c] = cp[0] + cp[1] + cp[2] + cp[3] + cp[4];
        }
        __syncthreads();
    }

    // pass-1 role (tid < 240): thread = (offset og, column cc); base column in registers
    const int og = tid / 20;
    const int cc = tid - og*20;
    const bool p1thr = (tid < OB*20);          // 240
    float bx[20], by[20], bz[20];
    if (p1thr) {
        #pragma unroll
        for (int r = 0; r < 20; ++r) {
            float4 v = sP[(SW_ + r)*SPS + (cc + SW_)];
            bx[r] = v.x; by[r] = v.y; bz[r] = v.z;
        }
    }

    // pass-2 role (tid 256..447): thread = (offset slot p2g, row p2i)
    const int t2 = tid - 256;
    const bool p2thr = (t2 >= 0 && t2 < OB*16); // 192
    const int p2g = p2thr ? (t2 >> 4) : 0;
    const int p2i = t2 & 15;

    // pass-3 role (tid >= 256): one thread per pixel, all offsets
    const bool p3thr = (tid >= 256);
    const int pix3 = tid & 255;
    const int tx3 = pix3 & 15, ty3 = pix3 >> 4;
    const float Sbase = sS[(ty3 + SW_)*SSS + (tx3 + SW_)];

    u32 kb[K_];
    #pragma unroll
    for (int k = 0; k < K_; ++k) kb[k] = 0xFFFFFFFFu;

    for (int i = 0; i <= NB + 1; ++i) {
        // ---- pass 1: batch i -> cs[i&1] (vertical box sums, register sliding window)
        if (i < NB && p1thr) {
            int ob, len; batch_of(q, i, ob, len);
            if (og < len) {
                int o = ob + og;
                u32 oyu = (u32)o / 15u, oxu = (u32)o - oyu*15u;
                const float4* sp = &sP[(int)oyu*SPS + cc + (int)oxu];
                float* myv = &cs[(i & 1)*CSBUF + og*CSOG + cc];
                float ring[5]; float run = 0.f;
                #pragma unroll
                for (int r = 0; r < 20; ++r) {
                    float4 sv = sp[r*SPS];
                    float hr = bx[r]*sv.x + by[r]*sv.y + bz[r]*sv.z;
                    if (r < 5) run += hr;
                    else       run += hr - ring[r % 5];
                    ring[r % 5] = hr;
                    if (r >= 4) myv[(r-4)*20] = run;
                }
            }
        }
        // ---- pass 2: batch i-1: cs[(i-1)&1] -> vb[(i-1)&1] (horizontal box sums)
        if (i >= 1 && i <= NB && p2thr) {
            int ob, len; batch_of(q, i - 1, ob, len);
            if (p2g < len) {
                const float* p2row = &cs[((i-1) & 1)*CSBUF + p2g*CSOG + p2i*20];
                float* vout = &vb[((i-1) & 1)*VBUF + p2g*VOG + p2i*16];
                float4 A = *(const float4*)(p2row);
                float4 B = *(const float4*)(p2row + 4);
                float4 Cv = *(const float4*)(p2row + 8);
                float4 Dv = *(const float4*)(p2row + 12);
                float4 Ev = *(const float4*)(p2row + 16);
                float v0=A.x,v1=A.y,v2=A.z,v3=A.w,v4=B.x,v5=B.y,v6=B.z,v7=B.w;
                float v8=Cv.x,v9=Cv.y,v10=Cv.z,v11=Cv.w,v12=Dv.x,v13=Dv.y,v14=Dv.z,v15=Dv.w;
                float v16=Ev.x,v17=Ev.y,v18=Ev.z,v19=Ev.w;
                float r0 = v0+v1+v2+v3+v4;
                float r1 = r0 + v5 - v0;
                float r2 = r1 + v6 - v1;
                float r3 = r2 + v7 - v2;
                float r4 = r3 + v8 - v3;
                float r5 = r4 + v9 - v4;
                float r6 = r5 + v10 - v5;
                float r7 = r6 + v11 - v6;
                float r8 = r7 + v12 - v7;
                float r9 = r8 + v13 - v8;
                float r10 = r9 + v14 - v9;
                float r11 = r10 + v15 - v10;
                float r12 = r11 + v16 - v11;
                float r13 = r12 + v17 - v12;
                float r14 = r13 + v18 - v13;
                float r15 = r14 + v19 - v14;
                *(float4*)(vout)      = make_float4(r0, r1, r2, r3);
                *(float4*)(vout + 4)  = make_float4(r4, r5, r6, r7);
                *(float4*)(vout + 8)  = make_float4(r8, r9, r10, r11);
                *(float4*)(vout + 12) = make_float4(r12, r13, r14, r15);
            }
        }
        // ---- pass 3: batch i-2: distance + branchless med3 insert (waves 4-7, all offsets)
        if (i >= 2 && p3thr) {
            int ob, len; batch_of(q, i - 2, ob, len);
            const float* vbase = &vb[((i-2) & 1)*VBUF + pix3];
            for (int g = 0; g < len; ++g) {
                int o2 = ob + g;
                u32 oy2 = (u32)o2 / 15u, ox2 = (u32)o2 - oy2*15u;
                float V = vbase[g*VOG];
                float d = fmaxf(Sbase + sS[(ty3 + (int)oy2)*SSS + (tx3 + (int)ox2)] - 2.f*V, 0.f);
                u32 c = (__float_as_uint(d) & 0xFFFFFF00u) | (u32)o2;
                #pragma unroll
                for (int k = K_-1; k > 0; --k) kb[k] = min(kb[k], max(kb[k-1], c));
                kb[0] = min(kb[0], c);
            }
        }
        __syncthreads();
    }

    // final write: threads 256+ hold the complete sorted list for their pixel
    if (p3thr) {
        int px = ((t*H_ + i0 + ty3)*W_ + j0 + tx3);
        uint4* pk = pkey + ((size_t)q*NPIX + px)*4;
        pk[0] = make_uint4(kb[0],  kb[1],  kb[2],  kb[3]);
        pk[1] = make_uint4(kb[4],  kb[5],  kb[6],  kb[7]);
        pk[2] = make_uint4(kb[8],  kb[9],  kb[10], kb[11]);
        pk[3] = make_uint4(kb[12], kb[13], 0xFFFFFFFFu, 0xFFFFFFFFu);
    }
}

// ---------------- Kernel 2: fused merge + softmax + gather-aggregate ----------------
// output padded coord y = i + PW_; contributing queries qi = y - a, a in [0,5)
// Planes packed as float2(x,y) + float(z): 2 LDS reads per (tap,k) instead of 3.
// Softmax via exp2f (native v_exp_f32) with folded 1/(denom*ln2).
__global__ __launch_bounds__(256, 4) void agg_kernel(const float* __restrict__ noisy,
                                                     const uint4* __restrict__ pkey,
                                                     const float* __restrict__ sigma,
                                                     float* __restrict__ out) {
    __shared__ float2 sPxy[APR*APS];
    __shared__ float  sPz[APR*APS];
    __shared__ float  sWt[AWR*AWR*AWS];
    __shared__ uint4  sIx[AWR*AWR];    // pre-decoded (dy<<4|dx) bytes

    const int tid = threadIdx.x;
    const int part = tid & 3;
    const int lp = tid >> 2;                  // 0..63 local pixel
    const int tx = lp & 7, ty = lp >> 3;
    const int i0 = blockIdx.y * AT, j0 = blockIdx.x * AT;
    const int t = blockIdx.z;

    // stage P planes directly from noisy (reflect + normalize fused)
    for (int e = tid; e < APR*APR; e += 256) {
        int r = e / APR, c = e - r*APR;
        float4 v = load_refl(noisy, t, i0 + 2 + r, j0 + 2 + c);
        sPxy[r*APS + c] = make_float2(v.x, v.y);
        sPz[r*APS + c]  = v.z;
    }

    // merge phase: one thread per staged neighbor (qi = i0 - 2 + r)
    if (tid < AWR*AWR) {
        int r = tid / AWR, c = tid - r*AWR;
        int qi = i0 - 2 + r, qj = j0 - 2 + c;
        if (qi >= 0 && qi < H_ && qj >= 0 && qj < W_) {
            size_t px = ((size_t)t*H_ + qi)*W_ + qj;
            // Batcher bitonic set-merge of the 2 sorted ascending 16-lists
            u32 A[16];
            {
                const uint4* pk = pkey + px*4;
                uint4 a0=pk[0], a1=pk[1], a2=pk[2], a3=pk[3];
                A[0]=a0.x; A[1]=a0.y; A[2]=a0.z; A[3]=a0.w;
                A[4]=a1.x; A[5]=a1.y; A[6]=a1.z; A[7]=a1.w;
                A[8]=a2.x; A[9]=a2.y; A[10]=a2.z; A[11]=a2.w;
                A[12]=a3.x; A[13]=a3.y; A[14]=a3.z; A[15]=a3.w;
            }
            {
                const uint4* pk = pkey + ((size_t)NPIX + px)*4;
                uint4 b0=pk[0], b1=pk[1], b2=pk[2], b3=pk[3];
                u32 B[16] = {b0.x,b0.y,b0.z,b0.w, b1.x,b1.y,b1.z,b1.w,
                             b2.x,b2.y,b2.z,b2.w, b3.x,b3.y,b3.z,b3.w};
                #pragma unroll
                for (int i2 = 0; i2 < 16; ++i2) A[i2] = min(A[i2], B[15 - i2]);
                #define CEX(x,y) { u32 mn = min(A[x],A[y]); u32 mx = max(A[x],A[y]); A[x]=mn; A[y]=mx; }
                CEX(0,8) CEX(1,9) CEX(2,10) CEX(3,11) CEX(4,12) CEX(5,13) CEX(6,14) CEX(7,15)
                CEX(0,4) CEX(1,5) CEX(2,6) CEX(3,7) CEX(8,12) CEX(9,13) CEX(10,14) CEX(11,15)
                CEX(0,2) CEX(1,3) CEX(4,6) CEX(5,7) CEX(8,10) CEX(9,11) CEX(12,14) CEX(13,15)
                CEX(0,1) CEX(2,3) CEX(4,5) CEX(6,7) CEX(8,9) CEX(10,11) CEX(12,13) CEX(14,15)
                #undef CEX
            }
            float sig = sigma[0] * (1.0f/255.0f) * 2.0f;
            float denom = 2.0f * (float)(C_*PS_*PS_) * (sig*sig) + 1e-8f;
            float c2 = 1.44269504088896f / denom;   // log2(e)/denom
            float d0 = __uint_as_float(A[0] & 0xFFFFFF00u);
            float w[K_]; float sum = 0.f;
            #pragma unroll
            for (int k = 0; k < K_; ++k) {
                float d = __uint_as_float(A[k] & 0xFFFFFF00u);
                w[k] = exp2f((d0 - d) * c2); sum += w[k];
            }
            float inv = 1.0f / sum;
            float4* dst = (float4*)&sWt[tid*AWS];
            dst[0] = make_float4(w[0]*inv,  w[1]*inv,  w[2]*inv,  w[3]*inv);
            dst[1] = make_float4(w[4]*inv,  w[5]*inv,  w[6]*inv,  w[7]*inv);
            dst[2] = make_float4(w[8]*inv,  w[9]*inv,  w[10]*inv, w[11]*inv);
            dst[3] = make_float4(w[12]*inv, w[13]*inv, 0.f, 0.f);
            // pre-decode offsets: byte = (dy<<4)|dx
            u32 db[K_];
            #pragma unroll
            for (int k = 0; k < K_; ++k) {
                u32 o_ = A[k] & 255u;
                u32 dy = o_ / 15u, dx = o_ - dy*15u;
                db[k] = (dy << 4) | dx;
            }
            uint4 iv;
            iv.x = db[0]  | (db[1]<<8)  | (db[2]<<16)  | (db[3]<<24);
            iv.y = db[4]  | (db[5]<<8)  | (db[6]<<16)  | (db[7]<<24);
            iv.z = db[8]  | (db[9]<<8)  | (db[10]<<16) | (db[11]<<24);
            iv.w = db[12] | (db[13]<<8);
            sIx[tid] = iv;
        }
    }
    __syncthreads();

    const int i = i0 + ty, j = j0 + tx;
    float s0 = 0.f, s1 = 0.f, s2 = 0.f;
    for (int ab = part; ab < 25; ab += 4) {
        int a = ab / 5, b = ab % 5;
        int qi = i + PW_ - a, qj = j + PW_ - b;
        if (qi < 0 || qi >= H_ || qj < 0 || qj >= W_) continue;
        int le = (ty + 4 - a)*AWR + (tx + 4 - b);   // (qi - (i0-2)) = ty + 4 - a
        const float4* wv = (const float4*)&sWt[le*AWS];
        float4 wa = wv[0], wb = wv[1], wc = wv[2], wd = wv[3];
        uint4 ip = sIx[le];
        #define ACC(wval, bbits) { \
            u32 b_ = (bbits); \
            int li = (ty + (int)(b_ >> 4))*APS + tx + (int)(b_ & 15u); \
            float w_ = (wval); \
            float2 vxy = sPxy[li]; \
            s0 += w_ * vxy.x; s1 += w_ * vxy.y; s2 += w_ * sPz[li]; }
        ACC(wa.x, ip.x & 255u);       ACC(wa.y, (ip.x>>8) & 255u);
        ACC(wa.z, (ip.x>>16) & 255u); ACC(wa.w, ip.x>>24);
        ACC(wb.x, ip.y & 255u);       ACC(wb.y, (ip.y>>8) & 255u);
        ACC(wb.z, (ip.y>>16) & 255u); ACC(wb.w, ip.y>>24);
        ACC(wc.x, ip.z & 255u);       ACC(wc.y, (ip.z>>8) & 255u);
        ACC(wc.z, (ip.z>>16) & 255u); ACC(wc.w, ip.z>>24);
        ACC(wd.x, ip.w & 255u);       ACC(wd.y, (ip.w>>8) & 255u);
        #undef ACC
    }

    s0 += __shfl_xor(s0, 1, 64); s0 += __shfl_xor(s0, 2, 64);
    s1 += __shfl_xor(s1, 1, 64); s1 += __shfl_xor(s1, 2, 64);
    s2 += __shfl_xor(s2, 1, 64); s2 += __shfl_xor(s2, 2, 64);

    if (part == 0) {
        // analytic count: a valid iff 0 <= i+2-a <= 127, a in [0,5)
        int na = min(4, i + 2) - max(0, i - 125) + 1;
        int nb = min(4, j + 2) - max(0, j - 125) + 1;
        float invc = 1.0f / ((float)(na * nb) + 1e-10f);
        size_t obase = (size_t)t*(C_*H_*W_) + (size_t)i*W_ + j;
        out[obase]             = 127.5f * (s0*invc + 1.0f);
        out[obase +   H_*W_]   = 127.5f * (s1*invc + 1.0f);
        out[obase + 2*(H_*W_)] = 127.5f * (s2*invc + 1.0f);
    }
}

extern "C" void kernel_launch(void* const* d_in, const int* in_sizes, int n_in,
                              void* d_out, int out_size, void* d_ws, size_t ws_size,
                              hipStream_t stream) {
    const float* noisy = (const float*)d_in[0];
    const float* sigma = (const float*)d_in[1];
    float* out = (float*)d_out;
    float* ws  = (float*)d_ws;

    // ws layout: pkey only = 2*NPIX*16 u32 = 8 MB
    uint4* pkey = (uint4*)ws;

    hipLaunchKernelGGL(fused_topk, dim3(W_/TILE, H_/TILE, T_*NQ), dim3(512), 0, stream,
                       noisy, pkey);

    hipLaunchKernelGGL(agg_kernel, dim3(W_/AT, H_/AT, T_), dim3(256), 0, stream,
                       noisy, pkey, sigma, out);
}